// Round 3
// baseline (659.627 us; speedup 1.0000x reference)
//
#include <hip/hip_runtime.h>
#include <math.h>

// Problem constants (match reference)
#define BATCH   131072
#define FEAT    256
#define NCLASS  50000
#define EPS     1e-12f
#define LAMBDA  0.5f

constexpr int WPB    = 4;              // waves per 256-thread block
constexpr int NBLK_M = BATCH  / WPB;   // 32768 main-pass blocks
constexpr int NBLK_C = NCLASS / WPB;   // 12500 scale-pass blocks

// v4 design: no sort, no scans, no gather. Center update decomposes as
//   out[c] = centers[c] * (1 - L*n/(1+n))  +  L/(1+n) * sum_rows fhat
// Pass 1 (scale_out): dense over classes, also emits sum_c n*||c||^2.
// Pass 2 (norm_atomic): stream feat rows; normalize in-wave; atomicAdd
//   L*w*fhat into out[label]; per-row loss ||fhat||^2 - 2*fhat.c_label
//   (centers row gathered, L3-hot after pass 1). 131K independent waves:
//   no per-segment latency chains, which is what bound v2/v3.
//
// ws layout (4B units): cnt[NCLASS] | pA[NBLK_M] | pC[NBLK_C]   (~380 KB)
// d_out: out[0]=loss ; out[1..] = new_centers.

__device__ __forceinline__ float wave_reduce_sum(float v) {
    #pragma unroll
    for (int m = 32; m; m >>= 1) v += __shfl_xor(v, m, 64);
    return v;
}

// ---- histogram ----
__global__ __launch_bounds__(256) void histo(const int* __restrict__ labels,
                                             int* __restrict__ cnt) {
    const int i = blockIdx.x * 256 + threadIdx.x;
    atomicAdd(&cnt[labels[i]], 1);
}

// ---- pass 1: scale centers into out, emit n*||c||^2 partials ----
__global__ __launch_bounds__(256) void scale_out(
        const float* __restrict__ centers,
        const int*   __restrict__ cnt,
        float*       __restrict__ outc,   // = out+1
        float*       __restrict__ pC) {
    const int wave = threadIdx.x >> 6;
    const int lane = threadIdx.x & 63;
    const int c    = blockIdx.x * WPB + wave;   // < NCLASS exactly

    const float4 cv = ((const float4*)(centers + (size_t)c * FEAT))[lane];
    const float fn = (float)cnt[c];
    const float s1 = 1.0f - LAMBDA * fn / (1.0f + fn);

    float4 nc;
    nc.x = cv.x * s1; nc.y = cv.y * s1; nc.z = cv.z * s1; nc.w = cv.w * s1;
    ((float4*)(outc + (size_t)c * FEAT))[lane] = nc;

    float lp = fn * (cv.x*cv.x + cv.y*cv.y + cv.z*cv.z + cv.w*cv.w);
    lp = wave_reduce_sum(lp);

    __shared__ float red[WPB];
    if (lane == 0) red[wave] = lp;
    __syncthreads();
    if (threadIdx.x == 0)
        pC[blockIdx.x] = red[0] + red[1] + red[2] + red[3];
}

// ---- pass 2: stream rows, normalize, atomic-accumulate, loss partial ----
__global__ __launch_bounds__(256) void norm_atomic(
        const float* __restrict__ feat,
        const int*   __restrict__ labels,
        const float* __restrict__ centers,
        const int*   __restrict__ cnt,
        float*       __restrict__ outc,   // = out+1  (pre-scaled by pass 1)
        float*       __restrict__ pA) {
    const int wave = threadIdx.x >> 6;
    const int lane = threadIdx.x & 63;
    const int row  = blockIdx.x * WPB + wave;   // linear -> coalesced read

    const float4 v   = ((const float4*)(feat + (size_t)row * FEAT))[lane];
    const int    lbl = labels[row];             // uniform per wave
    const float4 cv  = ((const float4*)(centers + (size_t)lbl * FEAT))[lane];

    // two independent butterflies interleaved: ||v||^2 and v.c
    float a = v.x*v.x + v.y*v.y + v.z*v.z + v.w*v.w;
    float b = v.x*cv.x + v.y*cv.y + v.z*cv.z + v.w*cv.w;
    #pragma unroll
    for (int m = 32; m; m >>= 1) {
        a += __shfl_xor(a, m, 64);
        b += __shfl_xor(b, m, 64);
    }

    const float rinv = 1.0f / fmaxf(sqrtf(a), EPS);
    const float w    = 1.0f / (1.0f + (float)cnt[lbl]);
    const float coef = LAMBDA * w * rinv;

    float* dst = outc + (size_t)lbl * FEAT + lane * 4;
    atomicAdd(dst + 0, v.x * coef);
    atomicAdd(dst + 1, v.y * coef);
    atomicAdd(dst + 2, v.z * coef);
    atomicAdd(dst + 3, v.w * coef);

    // per-row loss: ||fhat||^2 - 2*fhat.c   (wave-uniform)
    const float lp = (a * rinv) * rinv - 2.0f * (b * rinv);

    __shared__ float red[WPB];
    if (lane == 0) red[wave] = lp;
    __syncthreads();
    if (threadIdx.x == 0)
        pA[blockIdx.x] = red[0] + red[1] + red[2] + red[3];
}

// ---- final loss reduction ----
__global__ __launch_bounds__(1024) void finish(const float* __restrict__ pA,
                                               const float* __restrict__ pC,
                                               float* __restrict__ out0) {
    float s = 0.0f;
    for (int i = threadIdx.x; i < NBLK_M; i += 1024) s += pA[i];
    for (int i = threadIdx.x; i < NBLK_C; i += 1024) s += pC[i];
    s = wave_reduce_sum(s);
    __shared__ float red[16];
    const int wave = threadIdx.x >> 6;
    const int lane = threadIdx.x & 63;
    if (lane == 0) red[wave] = s;
    __syncthreads();
    if (threadIdx.x == 0) {
        float t = 0.0f;
        #pragma unroll
        for (int i = 0; i < 16; ++i) t += red[i];
        out0[0] = t * (1.0f / (float)BATCH);
    }
}

extern "C" void kernel_launch(void* const* d_in, const int* in_sizes, int n_in,
                              void* d_out, int out_size, void* d_ws, size_t ws_size,
                              hipStream_t stream) {
    const float* feat    = (const float*)d_in[0];
    const int*   labels  = (const int*)  d_in[1];
    const float* centers = (const float*)d_in[2];
    float* out = (float*)d_out;

    int*   cnt = (int*)d_ws;
    float* pA  = (float*)(cnt + NCLASS);
    float* pC  = pA + NBLK_M;

    hipMemsetAsync(cnt, 0, NCLASS * sizeof(int), stream);
    histo      <<<BATCH / 256, 256, 0, stream>>>(labels, cnt);
    scale_out  <<<NBLK_C, 256, 0, stream>>>(centers, cnt, out + 1, pC);
    norm_atomic<<<NBLK_M, 256, 0, stream>>>(feat, labels, centers, cnt,
                                            out + 1, pA);
    finish<<<1, 1024, 0, stream>>>(pA, pC, out);
}

// Round 4
// 285.018 us; speedup vs baseline: 2.3143x; 2.3143x over previous
//
#include <hip/hip_runtime.h>
#include <math.h>

// Problem constants (match reference)
#define BATCH   131072
#define FEAT    256
#define NCLASS  50000
#define EPS     1e-12f
#define LAMBDA  0.5f
#define CAP     32      // fallback-path bucket capacity

constexpr int WPB     = 4;                    // waves per 256-thread block
constexpr int CPW     = 8;                    // classes per wave (v5)
constexpr int CPB     = WPB * CPW;            // 32 classes per block
constexpr int NBLK_G  = (NCLASS + CPB - 1) / CPB;   // 1563
constexpr int NBLK_SS = NCLASS / WPB;         // 12500 (fallback)
constexpr int NSCAN   = (NCLASS + 255) / 256; // 196

// ws layout (4B units):
//   cnt[NCLASS] | cursor[NCLASS] | bsum[256] | boff[256] | pB[NBLK_G] | sIdx[BATCH]
// d_out: out[0]=loss ; out[1..] = new_centers.
//
// v5: one wave = 8 CONSECUTIVE classes. The scan makes their sorted rows one
// contiguous run of sIdx, so the row loop has cross-class ILP (v2's one-
// class-per-wave capped ILP at mean n=2.62 -> latency-bound, 88us). Class
// dispatch for the accumulate uses readfirstlane -> scalar branch, keeping
// acc[8] statically indexed (no scratch).

__device__ __forceinline__ float wave_reduce_sum(float v) {
    #pragma unroll
    for (int m = 32; m; m >>= 1) v += __shfl_xor(v, m, 64);
    return v;
}

// ---- histogram ----
__global__ __launch_bounds__(256) void histo(const int* __restrict__ labels,
                                             int* __restrict__ cnt) {
    const int i = blockIdx.x * 256 + threadIdx.x;
    atomicAdd(&cnt[labels[i]], 1);
}

// ---- multi-block exclusive scan of cnt -> cursor ----
__global__ __launch_bounds__(256) void scan_bsum(const int* __restrict__ cnt,
                                                 int* __restrict__ bsum) {
    __shared__ int s[256];
    const int i = blockIdx.x * 256 + threadIdx.x;
    s[threadIdx.x] = (i < NCLASS) ? cnt[i] : 0;
    __syncthreads();
    for (int off = 128; off; off >>= 1) {
        if (threadIdx.x < off) s[threadIdx.x] += s[threadIdx.x + off];
        __syncthreads();
    }
    if (threadIdx.x == 0) bsum[blockIdx.x] = s[0];
}

__global__ __launch_bounds__(256) void scan_boff(const int* __restrict__ bsum,
                                                 int* __restrict__ boff) {
    __shared__ int s[256];
    const int t = threadIdx.x;
    const int v = (t < NSCAN) ? bsum[t] : 0;
    s[t] = v;
    __syncthreads();
    for (int off = 1; off < 256; off <<= 1) {
        int u = (t >= off) ? s[t - off] : 0;
        __syncthreads();
        s[t] += u;
        __syncthreads();
    }
    if (t < NSCAN) boff[t] = s[t] - v;
}

__global__ __launch_bounds__(256) void scan_final(const int* __restrict__ cnt,
                                                  const int* __restrict__ boff,
                                                  int* __restrict__ cursor) {
    __shared__ int s[256];
    const int t = threadIdx.x;
    const int i = blockIdx.x * 256 + t;
    const int v = (i < NCLASS) ? cnt[i] : 0;
    s[t] = v;
    __syncthreads();
    for (int off = 1; off < 256; off <<= 1) {
        int u = (t >= off) ? s[t - off] : 0;
        __syncthreads();
        s[t] += u;
        __syncthreads();
    }
    if (i < NCLASS) cursor[i] = s[t] - v + boff[blockIdx.x];
}

// ---- scatter row indices into class-sorted order ----
__global__ __launch_bounds__(256) void scatter_idx(const int* __restrict__ labels,
                                                   int* __restrict__ cursor,  // -> end offsets
                                                   int* __restrict__ sIdx) {
    const int i = blockIdx.x * 256 + threadIdx.x;
    const int slot = atomicAdd(&cursor[labels[i]], 1);
    sIdx[slot] = i;
}

// ---- v5: 8-classes-per-wave fused gather + normalize + segsum + update ----
__global__ __launch_bounds__(256) void segsum_multi(
        const float* __restrict__ feat,
        const float* __restrict__ centers,
        const int*   __restrict__ cnt,
        const int*   __restrict__ cursor_end,   // end offsets (post-scatter)
        const int*   __restrict__ sIdx,
        float*       __restrict__ outc,         // = out+1
        float*       __restrict__ pB) {
    const int wave = threadIdx.x >> 6;
    const int lane = threadIdx.x & 63;
    const int c0   = (blockIdx.x * WPB + wave) * CPW;

    // per-class meta (wave-uniform values, computed in every lane)
    int e[CPW], nn[CPW];
    #pragma unroll
    for (int j = 0; j < CPW; ++j) {
        const int c = c0 + j;
        e[j]  = (c < NCLASS) ? cursor_end[c] : BATCH;   // cursor_end[NCLASS-1]==BATCH
        nn[j] = (c < NCLASS) ? cnt[c]        : 0;
    }
    const int S = e[0] - nn[0];          // first row of this wave's run
    const int R = e[CPW - 1] - S;        // total rows in run

    int B[CPW - 1];                      // class end-boundaries within run
    #pragma unroll
    for (int j = 0; j < CPW - 1; ++j) B[j] = e[j] - S;

    float4 acc[CPW];
    #pragma unroll
    for (int j = 0; j < CPW; ++j) acc[j] = make_float4(0.f, 0.f, 0.f, 0.f);
    float fsum2 = 0.f;                   // wave-uniform after butterflies

    for (int base = 0; base < R; base += 64) {
        int myidx = 0;
        int jcls  = 0;
        if (base + lane < R) myidx = sIdx[S + base + lane];
        {   // class of this lane's row (computed once per 64 rows)
            const int rr = base + lane;
            #pragma unroll
            for (int t = 0; t < CPW - 1; ++t) jcls += (rr >= B[t]) ? 1 : 0;
        }
        const int gn = min(64, R - base);

        for (int s = 0; s < gn; s += 4) {
            const int r0 = __shfl(myidx, s + 0, 64);
            const int r1 = __shfl(myidx, s + 1, 64);
            const int r2 = __shfl(myidx, s + 2, 64);
            const int r3 = __shfl(myidx, s + 3, 64);

            const float4 v0 = ((const float4*)(feat + (size_t)r0 * FEAT))[lane];
            const float4 v1 = ((const float4*)(feat + (size_t)r1 * FEAT))[lane];
            const float4 v2 = ((const float4*)(feat + (size_t)r2 * FEAT))[lane];
            const float4 v3 = ((const float4*)(feat + (size_t)r3 * FEAT))[lane];

            float a0 = v0.x*v0.x + v0.y*v0.y + v0.z*v0.z + v0.w*v0.w;
            float a1 = v1.x*v1.x + v1.y*v1.y + v1.z*v1.z + v1.w*v1.w;
            float a2 = v2.x*v2.x + v2.y*v2.y + v2.z*v2.z + v2.w*v2.w;
            float a3 = v3.x*v3.x + v3.y*v3.y + v3.z*v3.z + v3.w*v3.w;

            #pragma unroll
            for (int m = 32; m; m >>= 1) {       // 4 interleaved butterflies
                a0 += __shfl_xor(a0, m, 64);
                a1 += __shfl_xor(a1, m, 64);
                a2 += __shfl_xor(a2, m, 64);
                a3 += __shfl_xor(a3, m, 64);
            }

            const int rr = base + s;
            // coef = rinv, 0 for tail-padded rows (mask folded in)
            const float i0 = (rr + 0 < R) ? 1.0f / fmaxf(sqrtf(a0), EPS) : 0.f;
            const float i1 = (rr + 1 < R) ? 1.0f / fmaxf(sqrtf(a1), EPS) : 0.f;
            const float i2 = (rr + 2 < R) ? 1.0f / fmaxf(sqrtf(a2), EPS) : 0.f;
            const float i3 = (rr + 3 < R) ? 1.0f / fmaxf(sqrtf(a3), EPS) : 0.f;

            fsum2 += (a0*i0)*i0 + (a1*i1)*i1 + (a2*i2)*i2 + (a3*i3)*i3;

            // wave-uniform class ids -> scalar regs -> scalar branches
            const int j0 = __builtin_amdgcn_readfirstlane(__shfl(jcls, s + 0, 64));
            const int j1 = __builtin_amdgcn_readfirstlane(__shfl(jcls, s + 1, 64));
            const int j2 = __builtin_amdgcn_readfirstlane(__shfl(jcls, s + 2, 64));
            const int j3 = __builtin_amdgcn_readfirstlane(__shfl(jcls, s + 3, 64));

            #pragma unroll
            for (int t = 0; t < CPW; ++t) {
                if (t == j0) { acc[t].x += v0.x*i0; acc[t].y += v0.y*i0;
                               acc[t].z += v0.z*i0; acc[t].w += v0.w*i0; }
                if (t == j1) { acc[t].x += v1.x*i1; acc[t].y += v1.y*i1;
                               acc[t].z += v1.z*i1; acc[t].w += v1.w*i1; }
                if (t == j2) { acc[t].x += v2.x*i2; acc[t].y += v2.y*i2;
                               acc[t].z += v2.z*i2; acc[t].w += v2.w*i2; }
                if (t == j3) { acc[t].x += v3.x*i3; acc[t].y += v3.y*i3;
                               acc[t].z += v3.z*i3; acc[t].w += v3.w*i3; }
            }
        }
    }

    // epilogue: prefetch all 8 center rows, then update + loss
    float4 cv[CPW];
    #pragma unroll
    for (int j = 0; j < CPW; ++j) {
        const int c = c0 + j;
        cv[j] = (c < NCLASS)
              ? ((const float4*)(centers + (size_t)c * FEAT))[lane]
              : make_float4(0.f, 0.f, 0.f, 0.f);
    }

    float lp = 0.f;
    #pragma unroll
    for (int j = 0; j < CPW; ++j) {
        const int c  = c0 + j;
        const float fn = (float)nn[j];
        const float w  = 1.0f / (1.0f + fn);
        float4 nc;
        nc.x = cv[j].x - LAMBDA * (fn * cv[j].x - acc[j].x) * w;
        nc.y = cv[j].y - LAMBDA * (fn * cv[j].y - acc[j].y) * w;
        nc.z = cv[j].z - LAMBDA * (fn * cv[j].z - acc[j].z) * w;
        nc.w = cv[j].w - LAMBDA * (fn * cv[j].w - acc[j].w) * w;
        if (c < NCLASS)
            ((float4*)(outc + (size_t)c * FEAT))[lane] = nc;
        lp += fn * (cv[j].x*cv[j].x + cv[j].y*cv[j].y +
                    cv[j].z*cv[j].z + cv[j].w*cv[j].w)
            - 2.0f * (acc[j].x*cv[j].x + acc[j].y*cv[j].y +
                      acc[j].z*cv[j].z + acc[j].w*cv[j].w);
    }
    lp = wave_reduce_sum(lp);

    __shared__ float red[WPB];
    if (lane == 0) red[wave] = lp + fsum2;   // fsum2 is wave-uniform: add once
    __syncthreads();
    if (threadIdx.x == 0)
        pB[blockIdx.x] = red[0] + red[1] + red[2] + red[3];
}

// ---- final loss reduction ----
__global__ __launch_bounds__(1024) void finish(const float* __restrict__ pB,
                                               float* __restrict__ out0) {
    float s = 0.0f;
    for (int i = threadIdx.x; i < NBLK_G; i += 1024) s += pB[i];
    s = wave_reduce_sum(s);
    __shared__ float red[16];
    const int wave = threadIdx.x >> 6;
    const int lane = threadIdx.x & 63;
    if (lane == 0) red[wave] = s;
    __syncthreads();
    if (threadIdx.x == 0) {
        float t = 0.0f;
        #pragma unroll
        for (int i = 0; i < 16; ++i) t += red[i];
        out0[0] = t * (1.0f / (float)BATCH);
    }
}

// ================= fallback path (bucket gather) =================

__global__ __launch_bounds__(256) void scatter_bucket(const int* __restrict__ labels,
                                                      int* __restrict__ cnt,
                                                      int* __restrict__ bucket) {
    const int i = blockIdx.x * 256 + threadIdx.x;
    const int c = labels[i];
    const int slot = atomicAdd(&cnt[c], 1);
    if (slot < CAP) bucket[c * CAP + slot] = i;
}

__global__ __launch_bounds__(256) void gather_bucket(
        const float* __restrict__ feat, const float* __restrict__ centers,
        const int* __restrict__ cnt, const int* __restrict__ bucket,
        float* __restrict__ outc, float* __restrict__ pB) {
    const int wave = threadIdx.x >> 6;
    const int lane = threadIdx.x & 63;
    const int c    = blockIdx.x * WPB + wave;
    const int n = min(cnt[c], CAP);
    const int myidx = (lane < n) ? bucket[c * CAP + lane] : 0;
    float4 acc = {0.f,0.f,0.f,0.f};
    float fsum2 = 0.f;
    for (int s = 0; s < n; ++s) {
        const int r = __shfl(myidx, s, 64);
        const float4 v = ((const float4*)(feat + (size_t)r * FEAT))[lane];
        float ss = wave_reduce_sum(v.x*v.x + v.y*v.y + v.z*v.z + v.w*v.w);
        const float rinv = 1.0f / fmaxf(sqrtf(ss), EPS);
        acc.x += v.x*rinv; acc.y += v.y*rinv; acc.z += v.z*rinv; acc.w += v.w*rinv;
        fsum2 += ss * rinv * rinv;
    }
    const float4 cv = ((const float4*)(centers + (size_t)c * FEAT))[lane];
    const float fn = (float)n;
    const float w  = 1.0f / (1.0f + fn);
    float4 nc;
    nc.x = cv.x - LAMBDA * (fn*cv.x - acc.x) * w;
    nc.y = cv.y - LAMBDA * (fn*cv.y - acc.y) * w;
    nc.z = cv.z - LAMBDA * (fn*cv.z - acc.z) * w;
    nc.w = cv.w - LAMBDA * (fn*cv.w - acc.w) * w;
    ((float4*)(outc + (size_t)c * FEAT))[lane] = nc;
    float lp = fn * (cv.x*cv.x + cv.y*cv.y + cv.z*cv.z + cv.w*cv.w)
             - 2.0f * (acc.x*cv.x + acc.y*cv.y + acc.z*cv.z + acc.w*cv.w);
    lp = wave_reduce_sum(lp);
    __shared__ float red[WPB];
    if (lane == 0) red[wave] = lp + fsum2;
    __syncthreads();
    if (threadIdx.x == 0)
        pB[blockIdx.x] = red[0] + red[1] + red[2] + red[3];
}

__global__ __launch_bounds__(1024) void finishB(const float* __restrict__ pB,
                                                float* __restrict__ out0) {
    float s = 0.0f;
    for (int i = threadIdx.x; i < NBLK_SS; i += 1024) s += pB[i];
    s = wave_reduce_sum(s);
    __shared__ float red[16];
    const int wave = threadIdx.x >> 6;
    const int lane = threadIdx.x & 63;
    if (lane == 0) red[wave] = s;
    __syncthreads();
    if (threadIdx.x == 0) {
        float t = 0.0f;
        #pragma unroll
        for (int i = 0; i < 16; ++i) t += red[i];
        out0[0] = t * (1.0f / (float)BATCH);
    }
}

extern "C" void kernel_launch(void* const* d_in, const int* in_sizes, int n_in,
                              void* d_out, int out_size, void* d_ws, size_t ws_size,
                              hipStream_t stream) {
    const float* feat    = (const float*)d_in[0];
    const int*   labels  = (const int*)  d_in[1];
    const float* centers = (const float*)d_in[2];
    float* out = (float*)d_out;

    // fast path needs: cnt + cursor + bsum + boff + pB + sIdx  (~933 KB)
    const size_t need_fast =
        ((size_t)NCLASS * 2 + 512 + NBLK_G + BATCH) * 4;

    if (ws_size >= need_fast) {
        int*   cnt    = (int*)d_ws;
        int*   cursor = cnt + NCLASS;
        int*   bsum   = cursor + NCLASS;
        int*   boff   = bsum + 256;
        float* pB     = (float*)(boff + 256);
        int*   sIdx   = (int*)(pB + NBLK_G);

        hipMemsetAsync(cnt, 0, NCLASS * sizeof(int), stream);
        histo      <<<BATCH / 256, 256, 0, stream>>>(labels, cnt);
        scan_bsum  <<<NSCAN, 256, 0, stream>>>(cnt, bsum);
        scan_boff  <<<1, 256, 0, stream>>>(bsum, boff);
        scan_final <<<NSCAN, 256, 0, stream>>>(cnt, boff, cursor);
        scatter_idx<<<BATCH / 256, 256, 0, stream>>>(labels, cursor, sIdx);
        segsum_multi<<<NBLK_G, 256, 0, stream>>>(feat, centers, cnt, cursor,
                                                 sIdx, out + 1, pB);
        finish<<<1, 1024, 0, stream>>>(pB, out);
    } else {
        int*   cnt    = (int*)d_ws;
        int*   bucket = cnt + NCLASS;
        float* pB     = (float*)(bucket + (size_t)NCLASS * CAP);
        hipMemsetAsync(cnt, 0, NCLASS * sizeof(int), stream);
        scatter_bucket<<<BATCH / 256, 256, 0, stream>>>(labels, cnt, bucket);
        gather_bucket <<<NBLK_SS, 256, 0, stream>>>(feat, centers, cnt, bucket,
                                                    out + 1, pB);
        finishB<<<1, 1024, 0, stream>>>(pB, out);
    }
}

// Round 5
// 277.601 us; speedup vs baseline: 2.3762x; 1.0267x over previous
//
#include <hip/hip_runtime.h>
#include <math.h>

// Problem constants (match reference)
#define BATCH   131072
#define FEAT    256
#define NCLASS  50000
#define EPS     1e-12f
#define LAMBDA  0.5f
#define CAP     32      // fallback-path bucket capacity

constexpr int WPB     = 4;                    // waves per 256-thread block
constexpr int PBLK    = 2048;                 // persistent blocks (v6)
constexpr int TOTW    = PBLK * WPB;           // 8192 waves, grid-stride over classes
constexpr int NBLK_SS = NCLASS / WPB;         // 12500 (fallback)
constexpr int NSCAN   = (NCLASS + 255) / 256; // 196

// ws layout (4B units):
//   cnt[NCLASS] | cursor[NCLASS] | bsum[256] | boff[256] | pB[PBLK] | sIdx[BATCH]
// d_out: out[0]=loss ; out[1..] = new_centers.
//
// v6: persistent grid-stride waves, one class per iteration, 2-stage pipeline:
// while class k's 8 gathered feat loads are in flight, issue class k+1's
// meta -> sIdx slice -> centers row. Keeps ~10+ loads outstanding per wave
// continuously (v2 averaged ~2-3 -> 1.5 TB/s latency-bound). Loss partials
// accumulate per-lane across classes; ONE butterfly per wave at the end.

__device__ __forceinline__ float wave_reduce_sum(float v) {
    #pragma unroll
    for (int m = 32; m; m >>= 1) v += __shfl_xor(v, m, 64);
    return v;
}

// ---- histogram ----
__global__ __launch_bounds__(256) void histo(const int* __restrict__ labels,
                                             int* __restrict__ cnt) {
    const int i = blockIdx.x * 256 + threadIdx.x;
    atomicAdd(&cnt[labels[i]], 1);
}

// ---- multi-block exclusive scan of cnt -> cursor ----
__global__ __launch_bounds__(256) void scan_bsum(const int* __restrict__ cnt,
                                                 int* __restrict__ bsum) {
    __shared__ int s[256];
    const int i = blockIdx.x * 256 + threadIdx.x;
    s[threadIdx.x] = (i < NCLASS) ? cnt[i] : 0;
    __syncthreads();
    for (int off = 128; off; off >>= 1) {
        if (threadIdx.x < off) s[threadIdx.x] += s[threadIdx.x + off];
        __syncthreads();
    }
    if (threadIdx.x == 0) bsum[blockIdx.x] = s[0];
}

__global__ __launch_bounds__(256) void scan_boff(const int* __restrict__ bsum,
                                                 int* __restrict__ boff) {
    __shared__ int s[256];
    const int t = threadIdx.x;
    const int v = (t < NSCAN) ? bsum[t] : 0;
    s[t] = v;
    __syncthreads();
    for (int off = 1; off < 256; off <<= 1) {
        int u = (t >= off) ? s[t - off] : 0;
        __syncthreads();
        s[t] += u;
        __syncthreads();
    }
    if (t < NSCAN) boff[t] = s[t] - v;
}

__global__ __launch_bounds__(256) void scan_final(const int* __restrict__ cnt,
                                                  const int* __restrict__ boff,
                                                  int* __restrict__ cursor) {
    __shared__ int s[256];
    const int t = threadIdx.x;
    const int i = blockIdx.x * 256 + t;
    const int v = (i < NCLASS) ? cnt[i] : 0;
    s[t] = v;
    __syncthreads();
    for (int off = 1; off < 256; off <<= 1) {
        int u = (t >= off) ? s[t - off] : 0;
        __syncthreads();
        s[t] += u;
        __syncthreads();
    }
    if (i < NCLASS) cursor[i] = s[t] - v + boff[blockIdx.x];
}

// ---- scatter row indices into class-sorted order ----
__global__ __launch_bounds__(256) void scatter_idx(const int* __restrict__ labels,
                                                   int* __restrict__ cursor,  // -> end offsets
                                                   int* __restrict__ sIdx) {
    const int i = blockIdx.x * 256 + threadIdx.x;
    const int slot = atomicAdd(&cursor[labels[i]], 1);
    sIdx[slot] = i;
}

// ---- 8-row gather+normalize+accumulate burst (generic, for rows beyond the
//      pipelined first burst; rare at mean n=2.62) ----
__device__ __forceinline__ void burst8(const float* __restrict__ feat,
                                       int sidx, int lane, int s, int cc,
                                       float4& acc, float& fsum2) {
    const int r0 = __shfl(sidx, s + 0, 64);
    const int r1 = __shfl(sidx, s + 1, 64);
    const int r2 = __shfl(sidx, s + 2, 64);
    const int r3 = __shfl(sidx, s + 3, 64);
    const int r4 = __shfl(sidx, s + 4, 64);
    const int r5 = __shfl(sidx, s + 5, 64);
    const int r6 = __shfl(sidx, s + 6, 64);
    const int r7 = __shfl(sidx, s + 7, 64);

    const float4 v0 = ((const float4*)(feat + (size_t)r0 * FEAT))[lane];
    const float4 v1 = ((const float4*)(feat + (size_t)r1 * FEAT))[lane];
    const float4 v2 = ((const float4*)(feat + (size_t)r2 * FEAT))[lane];
    const float4 v3 = ((const float4*)(feat + (size_t)r3 * FEAT))[lane];
    const float4 v4 = ((const float4*)(feat + (size_t)r4 * FEAT))[lane];
    const float4 v5 = ((const float4*)(feat + (size_t)r5 * FEAT))[lane];
    const float4 v6 = ((const float4*)(feat + (size_t)r6 * FEAT))[lane];
    const float4 v7 = ((const float4*)(feat + (size_t)r7 * FEAT))[lane];

    float a0 = v0.x*v0.x + v0.y*v0.y + v0.z*v0.z + v0.w*v0.w;
    float a1 = v1.x*v1.x + v1.y*v1.y + v1.z*v1.z + v1.w*v1.w;
    float a2 = v2.x*v2.x + v2.y*v2.y + v2.z*v2.z + v2.w*v2.w;
    float a3 = v3.x*v3.x + v3.y*v3.y + v3.z*v3.z + v3.w*v3.w;
    float a4 = v4.x*v4.x + v4.y*v4.y + v4.z*v4.z + v4.w*v4.w;
    float a5 = v5.x*v5.x + v5.y*v5.y + v5.z*v5.z + v5.w*v5.w;
    float a6 = v6.x*v6.x + v6.y*v6.y + v6.z*v6.z + v6.w*v6.w;
    float a7 = v7.x*v7.x + v7.y*v7.y + v7.z*v7.z + v7.w*v7.w;

    #pragma unroll
    for (int m = 32; m; m >>= 1) {
        a0 += __shfl_xor(a0, m, 64); a1 += __shfl_xor(a1, m, 64);
        a2 += __shfl_xor(a2, m, 64); a3 += __shfl_xor(a3, m, 64);
        a4 += __shfl_xor(a4, m, 64); a5 += __shfl_xor(a5, m, 64);
        a6 += __shfl_xor(a6, m, 64); a7 += __shfl_xor(a7, m, 64);
    }

    const float i0 = (s + 0 < cc) ? 1.0f / fmaxf(sqrtf(a0), EPS) : 0.f;
    const float i1 = (s + 1 < cc) ? 1.0f / fmaxf(sqrtf(a1), EPS) : 0.f;
    const float i2 = (s + 2 < cc) ? 1.0f / fmaxf(sqrtf(a2), EPS) : 0.f;
    const float i3 = (s + 3 < cc) ? 1.0f / fmaxf(sqrtf(a3), EPS) : 0.f;
    const float i4 = (s + 4 < cc) ? 1.0f / fmaxf(sqrtf(a4), EPS) : 0.f;
    const float i5 = (s + 5 < cc) ? 1.0f / fmaxf(sqrtf(a5), EPS) : 0.f;
    const float i6 = (s + 6 < cc) ? 1.0f / fmaxf(sqrtf(a6), EPS) : 0.f;
    const float i7 = (s + 7 < cc) ? 1.0f / fmaxf(sqrtf(a7), EPS) : 0.f;

    acc.x += (v0.x*i0 + v1.x*i1) + (v2.x*i2 + v3.x*i3)
           + (v4.x*i4 + v5.x*i5) + (v6.x*i6 + v7.x*i7);
    acc.y += (v0.y*i0 + v1.y*i1) + (v2.y*i2 + v3.y*i3)
           + (v4.y*i4 + v5.y*i5) + (v6.y*i6 + v7.y*i7);
    acc.z += (v0.z*i0 + v1.z*i1) + (v2.z*i2 + v3.z*i3)
           + (v4.z*i4 + v5.z*i5) + (v6.z*i6 + v7.z*i7);
    acc.w += (v0.w*i0 + v1.w*i1) + (v2.w*i2 + v3.w*i3)
           + (v4.w*i4 + v5.w*i5) + (v6.w*i6 + v7.w*i7);

    fsum2 += ((a0*i0)*i0 + (a1*i1)*i1) + ((a2*i2)*i2 + (a3*i3)*i3)
           + ((a4*i4)*i4 + (a5*i5)*i5) + ((a6*i6)*i6 + (a7*i7)*i7);
}

// ---- v6: persistent pipelined segsum ----
__global__ __launch_bounds__(256) void segsum_persist(
        const float* __restrict__ feat,
        const float* __restrict__ centers,
        const int*   __restrict__ cnt,
        const int*   __restrict__ cursor_end,   // end offsets (post-scatter)
        const int*   __restrict__ sIdx,
        float*       __restrict__ outc,         // = out+1
        float*       __restrict__ pB) {
    const int wave = threadIdx.x >> 6;
    const int lane = threadIdx.x & 63;
    int c = blockIdx.x * WPB + wave;            // < 8192 <= NCLASS always

    float lp    = 0.f;   // per-lane loss partial, reduced once at the end
    float fsum2 = 0.f;   // wave-uniform

    // prologue: stage class c
    int n  = cnt[c];
    int st = cursor_end[c] - n;
    int sidx = (lane < n) ? sIdx[st + lane] : 0;
    float4 cv = ((const float4*)(centers + (size_t)c * FEAT))[lane];

    while (true) {
        const int c2 = c + TOTW;
        // (1) next class meta — in flight under everything below
        int n2 = 0, st2 = 0;
        if (c2 < NCLASS) { n2 = cnt[c2]; st2 = cursor_end[c2] - n2; }

        const int cn0 = min(n, 64);

        // (2) burst 0: issue 8 gathered loads for CURRENT class.
        //     Pad lanes carry sidx=0 -> L1-hot row 0, coefficient 0 below.
        const int r0 = __shfl(sidx, 0, 64);
        const int r1 = __shfl(sidx, 1, 64);
        const int r2 = __shfl(sidx, 2, 64);
        const int r3 = __shfl(sidx, 3, 64);
        const int r4 = __shfl(sidx, 4, 64);
        const int r5 = __shfl(sidx, 5, 64);
        const int r6 = __shfl(sidx, 6, 64);
        const int r7 = __shfl(sidx, 7, 64);
        const float4 v0 = ((const float4*)(feat + (size_t)r0 * FEAT))[lane];
        const float4 v1 = ((const float4*)(feat + (size_t)r1 * FEAT))[lane];
        const float4 v2 = ((const float4*)(feat + (size_t)r2 * FEAT))[lane];
        const float4 v3 = ((const float4*)(feat + (size_t)r3 * FEAT))[lane];
        const float4 v4 = ((const float4*)(feat + (size_t)r4 * FEAT))[lane];
        const float4 v5 = ((const float4*)(feat + (size_t)r5 * FEAT))[lane];
        const float4 v6 = ((const float4*)(feat + (size_t)r6 * FEAT))[lane];
        const float4 v7 = ((const float4*)(feat + (size_t)r7 * FEAT))[lane];

        // (3) next class sIdx slice + centers row; the meta-wait here
        //     overlaps the 8 feat loads already in flight.
        int sidx2 = 0;
        float4 cv2 = make_float4(0.f, 0.f, 0.f, 0.f);
        if (c2 < NCLASS) {
            if (lane < n2) sidx2 = sIdx[st2 + lane];
            cv2 = ((const float4*)(centers + (size_t)c2 * FEAT))[lane];
        }

        // (4) consume burst 0
        float4 acc = {0.f, 0.f, 0.f, 0.f};
        {
            float a0 = v0.x*v0.x + v0.y*v0.y + v0.z*v0.z + v0.w*v0.w;
            float a1 = v1.x*v1.x + v1.y*v1.y + v1.z*v1.z + v1.w*v1.w;
            float a2 = v2.x*v2.x + v2.y*v2.y + v2.z*v2.z + v2.w*v2.w;
            float a3 = v3.x*v3.x + v3.y*v3.y + v3.z*v3.z + v3.w*v3.w;
            float a4 = v4.x*v4.x + v4.y*v4.y + v4.z*v4.z + v4.w*v4.w;
            float a5 = v5.x*v5.x + v5.y*v5.y + v5.z*v5.z + v5.w*v5.w;
            float a6 = v6.x*v6.x + v6.y*v6.y + v6.z*v6.z + v6.w*v6.w;
            float a7 = v7.x*v7.x + v7.y*v7.y + v7.z*v7.z + v7.w*v7.w;
            #pragma unroll
            for (int m = 32; m; m >>= 1) {
                a0 += __shfl_xor(a0, m, 64); a1 += __shfl_xor(a1, m, 64);
                a2 += __shfl_xor(a2, m, 64); a3 += __shfl_xor(a3, m, 64);
                a4 += __shfl_xor(a4, m, 64); a5 += __shfl_xor(a5, m, 64);
                a6 += __shfl_xor(a6, m, 64); a7 += __shfl_xor(a7, m, 64);
            }
            const float i0 = (0 < cn0) ? 1.0f / fmaxf(sqrtf(a0), EPS) : 0.f;
            const float i1 = (1 < cn0) ? 1.0f / fmaxf(sqrtf(a1), EPS) : 0.f;
            const float i2 = (2 < cn0) ? 1.0f / fmaxf(sqrtf(a2), EPS) : 0.f;
            const float i3 = (3 < cn0) ? 1.0f / fmaxf(sqrtf(a3), EPS) : 0.f;
            const float i4 = (4 < cn0) ? 1.0f / fmaxf(sqrtf(a4), EPS) : 0.f;
            const float i5 = (5 < cn0) ? 1.0f / fmaxf(sqrtf(a5), EPS) : 0.f;
            const float i6 = (6 < cn0) ? 1.0f / fmaxf(sqrtf(a6), EPS) : 0.f;
            const float i7 = (7 < cn0) ? 1.0f / fmaxf(sqrtf(a7), EPS) : 0.f;

            acc.x += (v0.x*i0 + v1.x*i1) + (v2.x*i2 + v3.x*i3)
                   + (v4.x*i4 + v5.x*i5) + (v6.x*i6 + v7.x*i7);
            acc.y += (v0.y*i0 + v1.y*i1) + (v2.y*i2 + v3.y*i3)
                   + (v4.y*i4 + v5.y*i5) + (v6.y*i6 + v7.y*i7);
            acc.z += (v0.z*i0 + v1.z*i1) + (v2.z*i2 + v3.z*i3)
                   + (v4.z*i4 + v5.z*i5) + (v6.z*i6 + v7.z*i7);
            acc.w += (v0.w*i0 + v1.w*i1) + (v2.w*i2 + v3.w*i3)
                   + (v4.w*i4 + v5.w*i5) + (v6.w*i6 + v7.w*i7);

            fsum2 += ((a0*i0)*i0 + (a1*i1)*i1) + ((a2*i2)*i2 + (a3*i3)*i3)
                   + ((a4*i4)*i4 + (a5*i5)*i5) + ((a6*i6)*i6 + (a7*i7)*i7);
        }

        // remaining bursts of first chunk (n in (8,64], uncommon)
        for (int s = 8; s < cn0; s += 8)
            burst8(feat, sidx, lane, s, cn0, acc, fsum2);
        // chunks beyond 64 rows (rare)
        for (int base = 64; base < n; base += 64) {
            const int cc = min(64, n - base);
            const int sx = (base + lane < n) ? sIdx[st + base + lane] : 0;
            for (int s = 0; s < cc; s += 8)
                burst8(feat, sx, lane, s, cc, acc, fsum2);
        }

        // epilogue for class c (store is fire-and-forget)
        const float fn = (float)n;
        const float w  = 1.0f / (1.0f + fn);
        float4 nc;
        nc.x = cv.x - LAMBDA * (fn * cv.x - acc.x) * w;
        nc.y = cv.y - LAMBDA * (fn * cv.y - acc.y) * w;
        nc.z = cv.z - LAMBDA * (fn * cv.z - acc.z) * w;
        nc.w = cv.w - LAMBDA * (fn * cv.w - acc.w) * w;
        ((float4*)(outc + (size_t)c * FEAT))[lane] = nc;

        lp += fn * (cv.x*cv.x + cv.y*cv.y + cv.z*cv.z + cv.w*cv.w)
            - 2.0f * (acc.x*cv.x + acc.y*cv.y + acc.z*cv.z + acc.w*cv.w);

        if (c2 >= NCLASS) break;
        c = c2; n = n2; st = st2; sidx = sidx2; cv = cv2;   // rotate stage
    }

    lp = wave_reduce_sum(lp);
    __shared__ float red[WPB];
    if (lane == 0) red[wave] = lp + fsum2;   // fsum2 wave-uniform: add once
    __syncthreads();
    if (threadIdx.x == 0)
        pB[blockIdx.x] = red[0] + red[1] + red[2] + red[3];
}

// ---- final loss reduction ----
__global__ __launch_bounds__(1024) void finish(const float* __restrict__ pB,
                                               float* __restrict__ out0) {
    float s = 0.0f;
    for (int i = threadIdx.x; i < PBLK; i += 1024) s += pB[i];
    s = wave_reduce_sum(s);
    __shared__ float red[16];
    const int wave = threadIdx.x >> 6;
    const int lane = threadIdx.x & 63;
    if (lane == 0) red[wave] = s;
    __syncthreads();
    if (threadIdx.x == 0) {
        float t = 0.0f;
        #pragma unroll
        for (int i = 0; i < 16; ++i) t += red[i];
        out0[0] = t * (1.0f / (float)BATCH);
    }
}

// ================= fallback path (bucket gather) =================

__global__ __launch_bounds__(256) void scatter_bucket(const int* __restrict__ labels,
                                                      int* __restrict__ cnt,
                                                      int* __restrict__ bucket) {
    const int i = blockIdx.x * 256 + threadIdx.x;
    const int c = labels[i];
    const int slot = atomicAdd(&cnt[c], 1);
    if (slot < CAP) bucket[c * CAP + slot] = i;
}

__global__ __launch_bounds__(256) void gather_bucket(
        const float* __restrict__ feat, const float* __restrict__ centers,
        const int* __restrict__ cnt, const int* __restrict__ bucket,
        float* __restrict__ outc, float* __restrict__ pB) {
    const int wave = threadIdx.x >> 6;
    const int lane = threadIdx.x & 63;
    const int c    = blockIdx.x * WPB + wave;
    const int n = min(cnt[c], CAP);
    const int myidx = (lane < n) ? bucket[c * CAP + lane] : 0;
    float4 acc = {0.f,0.f,0.f,0.f};
    float fsum2 = 0.f;
    for (int s = 0; s < n; ++s) {
        const int r = __shfl(myidx, s, 64);
        const float4 v = ((const float4*)(feat + (size_t)r * FEAT))[lane];
        float ss = wave_reduce_sum(v.x*v.x + v.y*v.y + v.z*v.z + v.w*v.w);
        const float rinv = 1.0f / fmaxf(sqrtf(ss), EPS);
        acc.x += v.x*rinv; acc.y += v.y*rinv; acc.z += v.z*rinv; acc.w += v.w*rinv;
        fsum2 += ss * rinv * rinv;
    }
    const float4 cv = ((const float4*)(centers + (size_t)c * FEAT))[lane];
    const float fn = (float)n;
    const float w  = 1.0f / (1.0f + fn);
    float4 nc;
    nc.x = cv.x - LAMBDA * (fn*cv.x - acc.x) * w;
    nc.y = cv.y - LAMBDA * (fn*cv.y - acc.y) * w;
    nc.z = cv.z - LAMBDA * (fn*cv.z - acc.z) * w;
    nc.w = cv.w - LAMBDA * (fn*cv.w - acc.w) * w;
    ((float4*)(outc + (size_t)c * FEAT))[lane] = nc;
    float lp = fn * (cv.x*cv.x + cv.y*cv.y + cv.z*cv.z + cv.w*cv.w)
             - 2.0f * (acc.x*cv.x + acc.y*cv.y + acc.z*cv.z + acc.w*cv.w);
    lp = wave_reduce_sum(lp);
    __shared__ float red[WPB];
    if (lane == 0) red[wave] = lp + fsum2;
    __syncthreads();
    if (threadIdx.x == 0)
        pB[blockIdx.x] = red[0] + red[1] + red[2] + red[3];
}

__global__ __launch_bounds__(1024) void finishB(const float* __restrict__ pB,
                                                float* __restrict__ out0) {
    float s = 0.0f;
    for (int i = threadIdx.x; i < NBLK_SS; i += 1024) s += pB[i];
    s = wave_reduce_sum(s);
    __shared__ float red[16];
    const int wave = threadIdx.x >> 6;
    const int lane = threadIdx.x & 63;
    if (lane == 0) red[wave] = s;
    __syncthreads();
    if (threadIdx.x == 0) {
        float t = 0.0f;
        #pragma unroll
        for (int i = 0; i < 16; ++i) t += red[i];
        out0[0] = t * (1.0f / (float)BATCH);
    }
}

extern "C" void kernel_launch(void* const* d_in, const int* in_sizes, int n_in,
                              void* d_out, int out_size, void* d_ws, size_t ws_size,
                              hipStream_t stream) {
    const float* feat    = (const float*)d_in[0];
    const int*   labels  = (const int*)  d_in[1];
    const float* centers = (const float*)d_in[2];
    float* out = (float*)d_out;

    // fast path needs: cnt + cursor + bsum + boff + pB + sIdx  (~940 KB)
    const size_t need_fast =
        ((size_t)NCLASS * 2 + 512 + PBLK + BATCH) * 4;

    if (ws_size >= need_fast) {
        int*   cnt    = (int*)d_ws;
        int*   cursor = cnt + NCLASS;
        int*   bsum   = cursor + NCLASS;
        int*   boff   = bsum + 256;
        float* pB     = (float*)(boff + 256);
        int*   sIdx   = (int*)(pB + PBLK);

        hipMemsetAsync(cnt, 0, NCLASS * sizeof(int), stream);
        histo      <<<BATCH / 256, 256, 0, stream>>>(labels, cnt);
        scan_bsum  <<<NSCAN, 256, 0, stream>>>(cnt, bsum);
        scan_boff  <<<1, 256, 0, stream>>>(bsum, boff);
        scan_final <<<NSCAN, 256, 0, stream>>>(cnt, boff, cursor);
        scatter_idx<<<BATCH / 256, 256, 0, stream>>>(labels, cursor, sIdx);
        segsum_persist<<<PBLK, 256, 0, stream>>>(feat, centers, cnt, cursor,
                                                 sIdx, out + 1, pB);
        finish<<<1, 1024, 0, stream>>>(pB, out);
    } else {
        int*   cnt    = (int*)d_ws;
        int*   bucket = cnt + NCLASS;
        float* pB     = (float*)(bucket + (size_t)NCLASS * CAP);
        hipMemsetAsync(cnt, 0, NCLASS * sizeof(int), stream);
        scatter_bucket<<<BATCH / 256, 256, 0, stream>>>(labels, cnt, bucket);
        gather_bucket <<<NBLK_SS, 256, 0, stream>>>(feat, centers, cnt, bucket,
                                                    out + 1, pB);
        finishB<<<1, 1024, 0, stream>>>(pB, out);
    }
}